// Round 17
// baseline (186.562 us; speedup 1.0000x reference)
//
#include <hip/hip_runtime.h>
#include <hip/hip_bf16.h>

#define B 16
#define L 128
#define H 256
#define H2 512
#define P 16
#define EPSF 1e-8f
#define LDSTR 72   // shorts per LDS row (k_maxpool): 64 + 8 pad
#define ASTR 264   // shorts per As row (k_fused): 256 + 8 pad -> 528B stride, 2-way bank alias
#define PADQ 260   // floats per row for meanS/maxS
#define PATT 132

typedef __attribute__((ext_vector_type(8))) short short8;
typedef __attribute__((ext_vector_type(4))) short short4v;
typedef __attribute__((ext_vector_type(4))) float f32x4;

__device__ __forceinline__ short f2bf(float x) {
    unsigned u = __builtin_bit_cast(unsigned, x);
    u += 0x7fffu + ((u >> 16) & 1u);   // RNE; inputs finite
    return (short)(u >> 16);
}
__device__ __forceinline__ float bf2f(short s) {
    unsigned u = ((unsigned)(unsigned short)s) << 16;
    return __builtin_bit_cast(float, u);
}

// ---- Fused K1+K2+K3 (r14 lineage). v17: B-operand global->register.
// r16 lesson: phase 1 dominates k_fused; redundant phase-1 grid split was a
// net loss. Here phase 1 itself is cut down: each lane's MFMA B-fragment is
// 64 bf16 of its OWN row j0=wave*16+coll (k=ks*32+q*8+0..7), so B skips LDS
// entirely (load->cvt->reg, norm finished by 2 shfl_xor). A staged once at
// full width. Phase-1 barriers 9 -> 2; Bs LDS round-trip eliminated.
// Fragment k-ordering, att_s mapping, phases 2/3: verbatim r14. Grid back to
// 32x8 (r16's split reverted).
__global__ void __launch_bounds__(512) k_fused(
        const float* __restrict__ q1, const float* __restrict__ q2,
        const float* __restrict__ W, float* __restrict__ out) {
    int bd = blockIdx.x;
    int b = bd >> 1, dir = bd & 1;
    int m0 = blockIdx.y * 16;
    int t = threadIdx.x;
    int wave = t >> 6, l = t & 63, q = l >> 4, coll = l & 15;

    __shared__ __align__(16) short As[16 * ASTR];
    __shared__ __align__(16) float att_s[16][PATT];
    __shared__ __align__(16) float meanS[16][PADQ];
    __shared__ __align__(16) float maxS[16][PADQ];
    __shared__ __align__(16) float cful[256];
    __shared__ float nA[16];

    const float* q1b = q1 + ((size_t)b * L + m0) * H2 + dir * H;
    const float* q2b = q2 + (size_t)b * L * H2 + dir * H;

    // ---------------- phase 1: A->LDS (once, full width); B->registers ------
    float normA = 0.f;
    int arow = t >> 4, acol = (t & 15) * 4;   // t < 256 only
    for (int kt = 0; kt < 4; kt++) {
        if (t < 256) {
            int k0 = kt * 64;
            float4 va = *(const float4*)(q1b + (size_t)arow * H2 + k0 + acol);
            normA += va.x * va.x + va.y * va.y + va.z * va.z + va.w * va.w;
            short4v sa = { f2bf(va.x), f2bf(va.y), f2bf(va.z), f2bf(va.w) };
            *(short4v*)(As + arow * ASTR + k0 + acol) = sa;
        }
    }
    if (t < 256) {
        float sA = normA;
        for (int off = 1; off < 16; off <<= 1) sA += __shfl_xor(sA, off, 16);
        if ((t & 15) == 0) nA[arow] = sqrtf(sA);
        cful[t] = q2b[(size_t)(dir ? 0 : (L - 1)) * H2 + t];
    }

    // B-fragments: lane owns row j0, k = ks*32 + q*8 + (0..7)  [== old Bs read]
    int j0 = wave * 16 + coll;
    const float* bro = q2b + (size_t)j0 * H2 + q * 8;
    short8 bfrag[8];
    float normB = 0.f;
    for (int ks = 0; ks < 8; ks++) {
        float4 u0 = *(const float4*)(bro + ks * 32);
        float4 u1 = *(const float4*)(bro + ks * 32 + 4);
        normB += u0.x * u0.x + u0.y * u0.y + u0.z * u0.z + u0.w * u0.w
               + u1.x * u1.x + u1.y * u1.y + u1.z * u1.z + u1.w * u1.w;
        short8 s = { f2bf(u0.x), f2bf(u0.y), f2bf(u0.z), f2bf(u0.w),
                     f2bf(u1.x), f2bf(u1.y), f2bf(u1.z), f2bf(u1.w) };
        bfrag[ks] = s;
    }
    // row norm: sum the 4 q-groups (lanes l, l^16, l^32, l^48 share j0)
    normB += __shfl_xor(normB, 16, 64);
    normB += __shfl_xor(normB, 32, 64);
    float nBj = sqrtf(normB);

    __syncthreads();   // As, nA, cful visible

    f32x4 acc = (f32x4){0.f, 0.f, 0.f, 0.f};
    for (int ks = 0; ks < 8; ks++) {
        short8 af = *(const short8*)(As + coll * ASTR + ks * 32 + q * 8);
        acc = __builtin_amdgcn_mfma_f32_16x16x32_bf16(af, bfrag[ks], acc, 0, 0, 0);
    }
    {
        for (int r = 0; r < 4; r++) {
            float den = nA[q * 4 + r] * nBj;
            den = den > EPSF ? den : EPSF;
            att_s[q * 4 + r][j0] = acc[r] / den;
        }
    }
    __syncthreads();   // att_s visible

    // ---------------- phase 2: sum_j / max_j of att[i,j]*q2[j,h] (r14) ------
    int ig = t >> 6, hq = t & 63;
    int ia = ig * 2, ib = ia + 1;
    f32x4 s0 = (f32x4){0.f, 0.f, 0.f, 0.f}, s1 = s0;
    f32x4 mx0 = (f32x4){-INFINITY, -INFINITY, -INFINITY, -INFINITY}, mx1 = mx0;
    for (int j = 0; j < 128; j += 2) {
        float4 c0 = *(const float4*)(q2b + (size_t)j * H2 + hq * 4);
        float4 c1 = *(const float4*)(q2b + (size_t)(j + 1) * H2 + hq * 4);
        float wa0 = att_s[ia][j],     wb0 = att_s[ib][j];
        float wa1 = att_s[ia][j + 1], wb1 = att_s[ib][j + 1];
        f32x4 v0 = (f32x4){ wa0 * c0.x, wa0 * c0.y, wa0 * c0.z, wa0 * c0.w };
        f32x4 v1 = (f32x4){ wb0 * c0.x, wb0 * c0.y, wb0 * c0.z, wb0 * c0.w };
        f32x4 v2 = (f32x4){ wa1 * c1.x, wa1 * c1.y, wa1 * c1.z, wa1 * c1.w };
        f32x4 v3 = (f32x4){ wb1 * c1.x, wb1 * c1.y, wb1 * c1.z, wb1 * c1.w };
        s0 += v0; s0 += v2;
        s1 += v1; s1 += v3;
        mx0[0] = fmaxf(mx0[0], fmaxf(v0[0], v2[0]));
        mx0[1] = fmaxf(mx0[1], fmaxf(v0[1], v2[1]));
        mx0[2] = fmaxf(mx0[2], fmaxf(v0[2], v2[2]));
        mx0[3] = fmaxf(mx0[3], fmaxf(v0[3], v2[3]));
        mx1[0] = fmaxf(mx1[0], fmaxf(v1[0], v3[0]));
        mx1[1] = fmaxf(mx1[1], fmaxf(v1[1], v3[1]));
        mx1[2] = fmaxf(mx1[2], fmaxf(v1[2], v3[2]));
        mx1[3] = fmaxf(mx1[3], fmaxf(v1[3], v3[3]));
    }
    *(f32x4*)&meanS[ia][hq * 4] = s0;
    *(f32x4*)&meanS[ib][hq * 4] = s1;
    *(f32x4*)&maxS[ia][hq * 4] = mx0;
    *(f32x4*)&maxS[ib][hq * 4] = mx1;
    __syncthreads();   // meanS/maxS visible

    // ---------------- phase 3: cos_full pieces {full, attn, maxattn} (r14) --
    int p3 = t >> 5, i3 = (t >> 1) & 15, half = t & 1;
    const float* a3 = q1b + (size_t)i3 * H2;
    for (int pc = 0; pc < 3; pc++) {
        int widx = (pc == 0) ? dir : (pc == 1 ? 4 + dir : 6 + dir);
        const float* crow = (pc == 0) ? cful
                           : (pc == 1 ? &meanS[i3][0] : &maxS[i3][0]);
        const float* wg = W + (size_t)widx * 4096 + p3 * 256;
        float num = 0.f, na = 0.f, nc = 0.f;
        for (int ch = 0; ch < 32; ch++) {
            int h = half * 128 + ch * 4;
            float4 a4 = *(const float4*)(a3 + h);
            f32x4 c4 = *(const f32x4*)(crow + h);
            float4 w4 = *(const float4*)(wg + h);
            float ws0 = w4.x * w4.x, ws1 = w4.y * w4.y;
            float ws2 = w4.z * w4.z, ws3 = w4.w * w4.w;
            num += a4.x * c4[0] * ws0;
            na  += a4.x * a4.x * ws0;
            nc  += c4[0] * c4[0] * ws0;
            num += a4.y * c4[1] * ws1;
            na  += a4.y * a4.y * ws1;
            nc  += c4[1] * c4[1] * ws1;
            num += a4.z * c4[2] * ws2;
            na  += a4.z * a4.z * ws2;
            nc  += c4[2] * c4[2] * ws2;
            num += a4.w * c4[3] * ws3;
            na  += a4.w * a4.w * ws3;
            nc  += c4[3] * c4[3] * ws3;
        }
        num += __shfl_xor(num, 1, 2);
        na  += __shfl_xor(na, 1, 2);
        nc  += __shfl_xor(nc, 1, 2);
        if (half == 0) {
            float den = sqrtf(na) * sqrtf(nc);
            den = den > EPSF ? den : EPSF;
            int colbase = (pc == 0 ? 0 : pc == 1 ? 64 : 96) + dir * 16;
            out[((size_t)b * L + m0 + i3) * 128 + colbase + p3] = num / den;
        }
    }
}

// ---- K4: cos_maxpool via bf16 MFMA (r3-exact, untouched) --------------------
__global__ void __launch_bounds__(256, 2) k_maxpool_mfma(
        const float* __restrict__ q1, const float* __restrict__ q2,
        const float* __restrict__ W, float* __restrict__ out) {
    int bd = blockIdx.x;          // b*2 + dir
    int b = bd >> 1, dir = bd & 1;
    int p = blockIdx.y;
    int t = threadIdx.x;

    __shared__ __align__(16) short As[128 * LDSTR];
    __shared__ __align__(16) short Bs[128 * LDSTR];
    __shared__ float wv[H];
    __shared__ float nrm[256];    // [0..127]=||a_i||, [128..255]=||c_j||

    wv[t] = W[((size_t)(2 + dir) * P + p) * H + t];
    __syncthreads();

    f32x4 acc[2][8];
    for (int mt = 0; mt < 2; mt++)
        for (int nt = 0; nt < 8; nt++)
            acc[mt][nt] = (f32x4){0.f, 0.f, 0.f, 0.f};

    int lane16 = t & 15;
    int rgrp = t >> 4;
    int nrow = t & 127;
    int nmat = t >> 7;
    float normacc = 0.f;

    int wave = t >> 6;
    int l = t & 63;
    int q = l >> 4;
    int coll = l & 15;
    int m0 = wave * 32;

    const float* q1b = q1 + ((size_t)b * L) * H2 + dir * H;
    const float* q2b = q2 + ((size_t)b * L) * H2 + dir * H;

    for (int kt = 0; kt < 4; kt++) {
        int k0 = kt * 64;
        for (int pass = 0; pass < 8; pass++) {
            int row = rgrp + pass * 16;
            int c4 = lane16 * 4;
            float w0 = wv[k0 + c4], w1 = wv[k0 + c4 + 1];
            float w2 = wv[k0 + c4 + 2], w3 = wv[k0 + c4 + 3];
            float4 va = *(const float4*)(q1b + (size_t)row * H2 + k0 + c4);
            short4v sa = { f2bf(va.x * w0), f2bf(va.y * w1), f2bf(va.z * w2), f2bf(va.w * w3) };
            *(short4v*)(As + row * LDSTR + c4) = sa;
            float4 vb = *(const float4*)(q2b + (size_t)row * H2 + k0 + c4);
            short4v sb = { f2bf(vb.x * w0), f2bf(vb.y * w1), f2bf(vb.z * w2), f2bf(vb.w * w3) };
            *(short4v*)(Bs + row * LDSTR + c4) = sb;
        }
        __syncthreads();
        {
            const short* rowp = (nmat ? Bs : As) + nrow * LDSTR;
            for (int c = 0; c < 8; c++) {
                short8 s = *(const short8*)(rowp + c * 8);
                for (int jj = 0; jj < 8; jj++) {
                    float f = bf2f(s[jj]);
                    normacc += f * f;
                }
            }
        }
        for (int ks = 0; ks < 2; ks++) {
            int koff = ks * 32 + q * 8;
            short8 af0 = *(const short8*)(As + (m0 + coll) * LDSTR + koff);
            short8 af1 = *(const short8*)(As + (m0 + 16 + coll) * LDSTR + koff);
            for (int nt = 0; nt < 8; nt++) {
                short8 bfr = *(const short8*)(Bs + (nt * 16 + coll) * LDSTR + koff);
                acc[0][nt] = __builtin_amdgcn_mfma_f32_16x16x32_bf16(af0, bfr, acc[0][nt], 0, 0, 0);
                acc[1][nt] = __builtin_amdgcn_mfma_f32_16x16x32_bf16(af1, bfr, acc[1][nt], 0, 0, 0);
            }
        }
        __syncthreads();
    }
    nrm[t] = sqrtf(normacc);
    __syncthreads();

    float nav[2][4];
    for (int mt = 0; mt < 2; mt++)
        for (int r = 0; r < 4; r++)
            nav[mt][r] = nrm[m0 + mt * 16 + q * 4 + r];
    float rmax[2][4];
    for (int mt = 0; mt < 2; mt++)
        for (int r = 0; r < 4; r++) rmax[mt][r] = -INFINITY;
    for (int nt = 0; nt < 8; nt++) {
        float ncv = nrm[128 + nt * 16 + coll];
        for (int mt = 0; mt < 2; mt++)
            for (int r = 0; r < 4; r++) {
                float den = fmaxf(nav[mt][r] * ncv, EPSF);
                float v = acc[mt][nt][r] / den;
                rmax[mt][r] = fmaxf(rmax[mt][r], v);
            }
    }
    for (int off = 1; off < 16; off <<= 1)
        for (int mt = 0; mt < 2; mt++)
            for (int r = 0; r < 4; r++)
                rmax[mt][r] = fmaxf(rmax[mt][r], __shfl_xor(rmax[mt][r], off, 16));
    if (coll == 0) {
        for (int mt = 0; mt < 2; mt++)
            for (int r = 0; r < 4; r++) {
                int row = m0 + mt * 16 + q * 4 + r;
                out[((size_t)b * L + row) * 128 + 32 + dir * 16 + p] = rmax[mt][r];
            }
    }
}

extern "C" void kernel_launch(void* const* d_in, const int* in_sizes, int n_in,
                              void* d_out, int out_size, void* d_ws, size_t ws_size,
                              hipStream_t stream) {
    const float* q1 = (const float*)d_in[0];
    const float* q2 = (const float*)d_in[1];
    const float* W  = (const float*)d_in[2];
    float* out = (float*)d_out;
    (void)d_ws; (void)ws_size;   // workspace unused

    k_fused<<<dim3(B * 2, 8), 512, 0, stream>>>(q1, q2, W, out);
    k_maxpool_mfma<<<dim3(B * 2, P), 256, 0, stream>>>(q1, q2, W, out);
}

// Round 19
// 113.918 us; speedup vs baseline: 1.6377x; 1.6377x over previous
//
#include <hip/hip_runtime.h>
#include <hip/hip_bf16.h>

#define B 16
#define L 128
#define H 256
#define H2 512
#define P 16
#define EPSF 1e-8f
#define LDSTR 72   // shorts per LDS row: 64 + 8 pad
#define PADQ 260   // floats per row for meanS/maxS
#define PATT 132

typedef __attribute__((ext_vector_type(8))) short short8;
typedef __attribute__((ext_vector_type(4))) short short4v;
typedef __attribute__((ext_vector_type(4))) float f32x4;

__device__ __forceinline__ short f2bf(float x) {
    unsigned u = __builtin_bit_cast(unsigned, x);
    u += 0x7fffu + ((u >> 16) & 1u);   // RNE; inputs finite
    return (short)(u >> 16);
}
__device__ __forceinline__ float bf2f(short s) {
    unsigned u = ((unsigned)(unsigned short)s) << 16;
    return __builtin_bit_cast(float, u);
}

// ---- Fused K1+K2+K3 (r14 lineage). v18: phase 3 merged into ONE pass.
// r17 lesson: B->register was uncoalesced (row-strided lanes) -> reverted to
// r14's coalesced Bs staging. r16 lesson (corrected): phase 1 is ~7us; phases
// 2+3 (~48us) dominate, latency-stalled at 2 waves/SIMD. Phase 3 previously
// ran 3 sequential passes reloading a4 3x with 3 dependent loads/iter; now one
// pass: a4 loaded once, 7 independent loads/iter, 9 accumulators. Per-
// accumulator FP order identical to r14 -> bit-identical outputs.
// Phase 1, phase 2, k_maxpool: r14-verbatim. Grid 32x8.
__global__ void __launch_bounds__(512) k_fused(
        const float* __restrict__ q1, const float* __restrict__ q2,
        const float* __restrict__ W, float* __restrict__ out) {
    int bd = blockIdx.x;
    int b = bd >> 1, dir = bd & 1;
    int m0 = blockIdx.y * 16;
    int t = threadIdx.x;
    int wave = t >> 6, l = t & 63, q = l >> 4, coll = l & 15;

    __shared__ __align__(16) short As[16 * LDSTR];
    __shared__ __align__(16) short Bs[128 * LDSTR];
    __shared__ __align__(16) float att_s[16][PATT];
    __shared__ __align__(16) float meanS[16][PADQ];
    __shared__ __align__(16) float maxS[16][PADQ];
    __shared__ __align__(16) float cful[256];
    __shared__ float nA[16], nB[128];

    const float* q1b = q1 + ((size_t)b * L + m0) * H2 + dir * H;
    const float* q2b = q2 + (size_t)b * L * H2 + dir * H;

    // ---------------- phase 1: att tile [16 x 128] via bf16 MFMA (r14) ------
    f32x4 acc = (f32x4){0.f, 0.f, 0.f, 0.f};
    float normA = 0.f, normB = 0.f;
    int arow = t >> 4, acol = (t & 15) * 4;   // t < 256 only
    int brow = t >> 2, bc0 = (t & 3) * 16;

    for (int kt = 0; kt < 4; kt++) {
        int k0 = kt * 64;
        if (t < 256) {
            float4 va = *(const float4*)(q1b + (size_t)arow * H2 + k0 + acol);
            normA += va.x * va.x + va.y * va.y + va.z * va.z + va.w * va.w;
            short4v sa = { f2bf(va.x), f2bf(va.y), f2bf(va.z), f2bf(va.w) };
            *(short4v*)(As + arow * LDSTR + acol) = sa;
        }
        for (int cc = 0; cc < 4; cc++) {
            float4 vb = *(const float4*)(q2b + (size_t)brow * H2 + k0 + bc0 + cc * 4);
            normB += vb.x * vb.x + vb.y * vb.y + vb.z * vb.z + vb.w * vb.w;
            short4v sb = { f2bf(vb.x), f2bf(vb.y), f2bf(vb.z), f2bf(vb.w) };
            *(short4v*)(Bs + brow * LDSTR + bc0 + cc * 4) = sb;
        }
        __syncthreads();
        for (int ks = 0; ks < 2; ks++) {
            int koff = ks * 32 + q * 8;
            short8 af = *(const short8*)(As + coll * LDSTR + koff);
            short8 bf = *(const short8*)(Bs + (wave * 16 + coll) * LDSTR + koff);
            acc = __builtin_amdgcn_mfma_f32_16x16x32_bf16(af, bf, acc, 0, 0, 0);
        }
        __syncthreads();
    }
    if (t < 256) {
        float sA = normA;
        for (int off = 1; off < 16; off <<= 1) sA += __shfl_xor(sA, off, 16);
        if ((t & 15) == 0) nA[arow] = sqrtf(sA);
    }
    {
        float sB = normB;
        sB += __shfl_xor(sB, 1, 4);
        sB += __shfl_xor(sB, 2, 4);
        if ((t & 3) == 0) nB[brow] = sqrtf(sB);
    }
    __syncthreads();
    {
        float n2 = nB[wave * 16 + coll];
        for (int r = 0; r < 4; r++) {
            float den = nA[q * 4 + r] * n2;
            den = den > EPSF ? den : EPSF;
            att_s[q * 4 + r][wave * 16 + coll] = acc[r] / den;
        }
    }
    if (t < 256) cful[t] = q2b[(size_t)(dir ? 0 : (L - 1)) * H2 + t];
    __syncthreads();   // att_s/cful visible

    // ---------------- phase 2: sum_j / max_j of att[i,j]*q2[j,h] (r14) ------
    int ig = t >> 6, hq = t & 63;
    int ia = ig * 2, ib = ia + 1;
    f32x4 s0 = (f32x4){0.f, 0.f, 0.f, 0.f}, s1 = s0;
    f32x4 mx0 = (f32x4){-INFINITY, -INFINITY, -INFINITY, -INFINITY}, mx1 = mx0;
    for (int j = 0; j < 128; j += 2) {
        float4 c0 = *(const float4*)(q2b + (size_t)j * H2 + hq * 4);
        float4 c1 = *(const float4*)(q2b + (size_t)(j + 1) * H2 + hq * 4);
        float wa0 = att_s[ia][j],     wb0 = att_s[ib][j];
        float wa1 = att_s[ia][j + 1], wb1 = att_s[ib][j + 1];
        f32x4 v0 = (f32x4){ wa0 * c0.x, wa0 * c0.y, wa0 * c0.z, wa0 * c0.w };
        f32x4 v1 = (f32x4){ wb0 * c0.x, wb0 * c0.y, wb0 * c0.z, wb0 * c0.w };
        f32x4 v2 = (f32x4){ wa1 * c1.x, wa1 * c1.y, wa1 * c1.z, wa1 * c1.w };
        f32x4 v3 = (f32x4){ wb1 * c1.x, wb1 * c1.y, wb1 * c1.z, wb1 * c1.w };
        s0 += v0; s0 += v2;
        s1 += v1; s1 += v3;
        mx0[0] = fmaxf(mx0[0], fmaxf(v0[0], v2[0]));
        mx0[1] = fmaxf(mx0[1], fmaxf(v0[1], v2[1]));
        mx0[2] = fmaxf(mx0[2], fmaxf(v0[2], v2[2]));
        mx0[3] = fmaxf(mx0[3], fmaxf(v0[3], v2[3]));
        mx1[0] = fmaxf(mx1[0], fmaxf(v1[0], v3[0]));
        mx1[1] = fmaxf(mx1[1], fmaxf(v1[1], v3[1]));
        mx1[2] = fmaxf(mx1[2], fmaxf(v1[2], v3[2]));
        mx1[3] = fmaxf(mx1[3], fmaxf(v1[3], v3[3]));
    }
    *(f32x4*)&meanS[ia][hq * 4] = s0;
    *(f32x4*)&meanS[ib][hq * 4] = s1;
    *(f32x4*)&maxS[ia][hq * 4] = mx0;
    *(f32x4*)&maxS[ib][hq * 4] = mx1;
    __syncthreads();   // meanS/maxS visible

    // ------- phase 3 (v18): all 3 cos_full pieces in ONE pass over h --------
    int p3 = t >> 5, i3 = (t >> 1) & 15, half = t & 1;
    const float* a3 = q1b + (size_t)i3 * H2;
    const float* wg0 = W + (size_t)dir * 4096 + p3 * 256;
    const float* wg1 = W + (size_t)(4 + dir) * 4096 + p3 * 256;
    const float* wg2 = W + (size_t)(6 + dir) * 4096 + p3 * 256;
    const float* cm = &meanS[i3][0];
    const float* cx = &maxS[i3][0];
    float num0 = 0.f, na0 = 0.f, nc0 = 0.f;
    float num1 = 0.f, na1 = 0.f, nc1 = 0.f;
    float num2 = 0.f, na2 = 0.f, nc2 = 0.f;
    for (int ch = 0; ch < 32; ch++) {
        int h = half * 128 + ch * 4;
        float4 a4 = *(const float4*)(a3 + h);
        f32x4 c0 = *(const f32x4*)(cful + h);
        f32x4 c1 = *(const f32x4*)(cm + h);
        f32x4 c2 = *(const f32x4*)(cx + h);
        float4 w0 = *(const float4*)(wg0 + h);
        float4 w1 = *(const float4*)(wg1 + h);
        float4 w2 = *(const float4*)(wg2 + h);
        float av[4] = { a4.x, a4.y, a4.z, a4.w };
        float ww0[4] = { w0.x * w0.x, w0.y * w0.y, w0.z * w0.z, w0.w * w0.w };
        float ww1[4] = { w1.x * w1.x, w1.y * w1.y, w1.z * w1.z, w1.w * w1.w };
        float ww2[4] = { w2.x * w2.x, w2.y * w2.y, w2.z * w2.z, w2.w * w2.w };
#pragma unroll
        for (int e = 0; e < 4; e++) {
            num0 += av[e] * c0[e] * ww0[e];
            na0  += av[e] * av[e] * ww0[e];
            nc0  += c0[e] * c0[e] * ww0[e];
            num1 += av[e] * c1[e] * ww1[e];
            na1  += av[e] * av[e] * ww1[e];
            nc1  += c1[e] * c1[e] * ww1[e];
            num2 += av[e] * c2[e] * ww2[e];
            na2  += av[e] * av[e] * ww2[e];
            nc2  += c2[e] * c2[e] * ww2[e];
        }
    }
    num0 += __shfl_xor(num0, 1, 2);
    na0  += __shfl_xor(na0, 1, 2);
    nc0  += __shfl_xor(nc0, 1, 2);
    num1 += __shfl_xor(num1, 1, 2);
    na1  += __shfl_xor(na1, 1, 2);
    nc1  += __shfl_xor(nc1, 1, 2);
    num2 += __shfl_xor(num2, 1, 2);
    na2  += __shfl_xor(na2, 1, 2);
    nc2  += __shfl_xor(nc2, 1, 2);
    if (half == 0) {
        size_t orow = ((size_t)b * L + m0 + i3) * 128;
        float d0 = sqrtf(na0) * sqrtf(nc0);
        d0 = d0 > EPSF ? d0 : EPSF;
        out[orow + 0 + dir * 16 + p3] = num0 / d0;
        float d1 = sqrtf(na1) * sqrtf(nc1);
        d1 = d1 > EPSF ? d1 : EPSF;
        out[orow + 64 + dir * 16 + p3] = num1 / d1;
        float d2 = sqrtf(na2) * sqrtf(nc2);
        d2 = d2 > EPSF ? d2 : EPSF;
        out[orow + 96 + dir * 16 + p3] = num2 / d2;
    }
}

// ---- K4: cos_maxpool via bf16 MFMA (r3-exact, untouched) --------------------
__global__ void __launch_bounds__(256, 2) k_maxpool_mfma(
        const float* __restrict__ q1, const float* __restrict__ q2,
        const float* __restrict__ W, float* __restrict__ out) {
    int bd = blockIdx.x;          // b*2 + dir
    int b = bd >> 1, dir = bd & 1;
    int p = blockIdx.y;
    int t = threadIdx.x;

    __shared__ __align__(16) short As[128 * LDSTR];
    __shared__ __align__(16) short Bs[128 * LDSTR];
    __shared__ float wv[H];
    __shared__ float nrm[256];    // [0..127]=||a_i||, [128..255]=||c_j||

    wv[t] = W[((size_t)(2 + dir) * P + p) * H + t];
    __syncthreads();

    f32x4 acc[2][8];
    for (int mt = 0; mt < 2; mt++)
        for (int nt = 0; nt < 8; nt++)
            acc[mt][nt] = (f32x4){0.f, 0.f, 0.f, 0.f};

    int lane16 = t & 15;
    int rgrp = t >> 4;
    int nrow = t & 127;
    int nmat = t >> 7;
    float normacc = 0.f;

    int wave = t >> 6;
    int l = t & 63;
    int q = l >> 4;
    int coll = l & 15;
    int m0 = wave * 32;

    const float* q1b = q1 + ((size_t)b * L) * H2 + dir * H;
    const float* q2b = q2 + ((size_t)b * L) * H2 + dir * H;

    for (int kt = 0; kt < 4; kt++) {
        int k0 = kt * 64;
        for (int pass = 0; pass < 8; pass++) {
            int row = rgrp + pass * 16;
            int c4 = lane16 * 4;
            float w0 = wv[k0 + c4], w1 = wv[k0 + c4 + 1];
            float w2 = wv[k0 + c4 + 2], w3 = wv[k0 + c4 + 3];
            float4 va = *(const float4*)(q1b + (size_t)row * H2 + k0 + c4);
            short4v sa = { f2bf(va.x * w0), f2bf(va.y * w1), f2bf(va.z * w2), f2bf(va.w * w3) };
            *(short4v*)(As + row * LDSTR + c4) = sa;
            float4 vb = *(const float4*)(q2b + (size_t)row * H2 + k0 + c4);
            short4v sb = { f2bf(vb.x * w0), f2bf(vb.y * w1), f2bf(vb.z * w2), f2bf(vb.w * w3) };
            *(short4v*)(Bs + row * LDSTR + c4) = sb;
        }
        __syncthreads();
        {
            const short* rowp = (nmat ? Bs : As) + nrow * LDSTR;
            for (int c = 0; c < 8; c++) {
                short8 s = *(const short8*)(rowp + c * 8);
                for (int jj = 0; jj < 8; jj++) {
                    float f = bf2f(s[jj]);
                    normacc += f * f;
                }
            }
        }
        for (int ks = 0; ks < 2; ks++) {
            int koff = ks * 32 + q * 8;
            short8 af0 = *(const short8*)(As + (m0 + coll) * LDSTR + koff);
            short8 af1 = *(const short8*)(As + (m0 + 16 + coll) * LDSTR + koff);
            for (int nt = 0; nt < 8; nt++) {
                short8 bfr = *(const short8*)(Bs + (nt * 16 + coll) * LDSTR + koff);
                acc[0][nt] = __builtin_amdgcn_mfma_f32_16x16x32_bf16(af0, bfr, acc[0][nt], 0, 0, 0);
                acc[1][nt] = __builtin_amdgcn_mfma_f32_16x16x32_bf16(af1, bfr, acc[1][nt], 0, 0, 0);
            }
        }
        __syncthreads();
    }
    nrm[t] = sqrtf(normacc);
    __syncthreads();

    float nav[2][4];
    for (int mt = 0; mt < 2; mt++)
        for (int r = 0; r < 4; r++)
            nav[mt][r] = nrm[m0 + mt * 16 + q * 4 + r];
    float rmax[2][4];
    for (int mt = 0; mt < 2; mt++)
        for (int r = 0; r < 4; r++) rmax[mt][r] = -INFINITY;
    for (int nt = 0; nt < 8; nt++) {
        float ncv = nrm[128 + nt * 16 + coll];
        for (int mt = 0; mt < 2; mt++)
            for (int r = 0; r < 4; r++) {
                float den = fmaxf(nav[mt][r] * ncv, EPSF);
                float v = acc[mt][nt][r] / den;
                rmax[mt][r] = fmaxf(rmax[mt][r], v);
            }
    }
    for (int off = 1; off < 16; off <<= 1)
        for (int mt = 0; mt < 2; mt++)
            for (int r = 0; r < 4; r++)
                rmax[mt][r] = fmaxf(rmax[mt][r], __shfl_xor(rmax[mt][r], off, 16));
    if (coll == 0) {
        for (int mt = 0; mt < 2; mt++)
            for (int r = 0; r < 4; r++) {
                int row = m0 + mt * 16 + q * 4 + r;
                out[((size_t)b * L + row) * 128 + 32 + dir * 16 + p] = rmax[mt][r];
            }
    }
}

extern "C" void kernel_launch(void* const* d_in, const int* in_sizes, int n_in,
                              void* d_out, int out_size, void* d_ws, size_t ws_size,
                              hipStream_t stream) {
    const float* q1 = (const float*)d_in[0];
    const float* q2 = (const float*)d_in[1];
    const float* W  = (const float*)d_in[2];
    float* out = (float*)d_out;
    (void)d_ws; (void)ws_size;   // workspace unused

    k_fused<<<dim3(B * 2, 8), 512, 0, stream>>>(q1, q2, W, out);
    k_maxpool_mfma<<<dim3(B * 2, P), 256, 0, stream>>>(q1, q2, W, out);
}